// Round 2
// baseline (66.650 us; speedup 1.0000x reference)
//
#include <hip/hip_runtime.h>
#include <math.h>

#define EPSF 1e-5f
#define N_B 16
#define C_CH 128
#define T_LEN 513
#define NI 257
#define NJ 256
#define T_CUT -5.0f

// workspace layout (floats)
#define D2P_OFF  0                       // [16][16][513] = 131,328
#define CORR_OFF 131328                  // [16][257][256] = 1,052,672 (CORR in, RAM out, in-place)
#define PDA_OFF  1184000                 // [16][5][256]  = 20,480
#define RS_OFF   1204480                 // [16][257]     = 4,112
// total 1,208,592 floats = 4.83 MB

// ---- K1: per-(n, c-block-of-8) partial sums of x^2 over c, for every t; zero CORR
__global__ __launch_bounds__(512) void k_prep(const float* __restrict__ x,
                                              float* __restrict__ d2p,
                                              float* __restrict__ corr) {
    const int n = blockIdx.x, cb = blockIdx.y;
    const int t = threadIdx.x;
    const float* xn = x + (size_t)(n * C_CH + cb * 8) * T_LEN;
    // zero the correction buffer (stream order guarantees completion before k_corr)
    {
        const int chunk = (NI * NJ) / 16;                  // 4112
        size_t base = (size_t)n * NI * NJ + (size_t)cb * chunk;
        for (int k = t; k < chunk; k += 512) corr[base + k] = 0.f;
    }
    float s = 0.f;
    #pragma unroll
    for (int cc = 0; cc < 8; ++cc) { float v = xn[cc * T_LEN + t]; s += v * v; }
    d2p[(n * 16 + cb) * T_LEN + t] = s;
    if (t == 0) {
        float s2 = 0.f;
        #pragma unroll
        for (int cc = 0; cc < 8; ++cc) { float v = xn[cc * T_LEN + 512]; s2 += v * v; }
        d2p[(n * 16 + cb) * T_LEN + 512] = s2;
    }
}

// ---- K2: sparse eps-tail corrections: for pairs with d = x1-x2 < -5,
//      add 2dh + h^2, h = log1p(eps*exp(-d)).  One wave per (n,c).
__global__ __launch_bounds__(256) void k_corr(const float* __restrict__ x,
                                              float* __restrict__ corr) {
    const int wv = (blockIdx.x * 256 + threadIdx.x) >> 6;   // 0..2047
    const int lane = threadIdx.x & 63;
    const int n = wv >> 7, c = wv & 127;
    const float* xr = x + (size_t)(n * C_CH + c) * T_LEN;
    float r2[4];
    #pragma unroll
    for (int k = 0; k < 4; ++k) r2[k] = xr[2 * (lane + 64 * k) + 1];
    float M2 = fmaxf(fmaxf(r2[0], r2[1]), fmaxf(r2[2], r2[3]));
    #pragma unroll
    for (int off = 32; off; off >>= 1) M2 = fmaxf(M2, __shfl_xor(M2, off, 64));
    const float thr = M2 + T_CUT;                            // need x1 < M2 - 5
    float* cn = corr + (size_t)n * NI * NJ;
    for (int k4 = 0; k4 < 5; ++k4) {
        const int i = k4 * 64 + lane;
        const float v1 = (i < NI) ? xr[2 * i] : 1e30f;
        unsigned long long mask = __ballot(v1 < thr);
        while (mask) {
            const int s = __builtin_ctzll(mask); mask &= mask - 1;
            const float xi = __shfl(v1, s, 64);
            const int ii = k4 * 64 + s;
            #pragma unroll
            for (int k = 0; k < 4; ++k) {
                const float d = xi - r2[k];
                if (d < T_CUT) {
                    const float h = log1pf(EPSF * __expf(-d));
                    atomicAdd(&cn[ii * NJ + lane + 64 * k], fmaf(2.f * d, h, h * h));
                }
            }
        }
    }
}

// ---- K3: fp32 cross-GEMM + epilogue: RAM = exp2((P+Q-2*CROSS+CORR)*log2e/128),
//      also per-block partial column sums pda[n][ib][j].
__global__ __launch_bounds__(256) void k_gemm(const float* __restrict__ x,
                                              const float* __restrict__ d2p,
                                              float* __restrict__ ramio,
                                              float* __restrict__ pda) {
    const int n = blockIdx.z, ib = blockIdx.y, jb = blockIdx.x;
    const int i0 = ib * 64, j0 = jb * 64;
    __shared__ float s1[16][64];
    __shared__ float s2[16][64];
    __shared__ float Ps[64], Qs[64];
    const int tid = threadIdx.x;
    const int tx = tid & 15, ty = tid >> 4;
    float acc[4][4] = {{0.f}};
    const float* xn = x + (size_t)n * C_CH * T_LEN;

    for (int c0 = 0; c0 < C_CH; c0 += 16) {
        #pragma unroll
        for (int k = 0; k < 4; ++k) {
            const int f = tid + 256 * k;
            const int cc = f >> 6, e = f & 63;
            int ti = 2 * (i0 + e); if (ti > 512) ti = 512;   // clamp, discarded later
            s1[cc][e] = xn[(c0 + cc) * T_LEN + ti];
            s2[cc][e] = xn[(c0 + cc) * T_LEN + 2 * (j0 + e) + 1];
        }
        __syncthreads();
        #pragma unroll
        for (int cc = 0; cc < 16; ++cc) {
            const float4 a = *(const float4*)&s1[cc][4 * ty];
            const float4 b = *(const float4*)&s2[cc][4 * tx];
            acc[0][0] += a.x * b.x; acc[0][1] += a.x * b.y; acc[0][2] += a.x * b.z; acc[0][3] += a.x * b.w;
            acc[1][0] += a.y * b.x; acc[1][1] += a.y * b.y; acc[1][2] += a.y * b.z; acc[1][3] += a.y * b.w;
            acc[2][0] += a.z * b.x; acc[2][1] += a.z * b.y; acc[2][2] += a.z * b.z; acc[2][3] += a.z * b.w;
            acc[3][0] += a.w * b.x; acc[3][1] += a.w * b.y; acc[3][2] += a.w * b.z; acc[3][3] += a.w * b.w;
        }
        __syncthreads();
    }
    // P_i, Q_j from the c-partials
    if (tid < 64) {
        const int i = i0 + tid; float s = 0.f;
        if (i < NI) {
            #pragma unroll
            for (int k = 0; k < 16; ++k) s += d2p[(n * 16 + k) * T_LEN + 2 * i];
        }
        Ps[tid] = s;
    } else if (tid < 128) {
        const int j = j0 + tid - 64; float s = 0.f;
        #pragma unroll
        for (int k = 0; k < 16; ++k) s += d2p[(n * 16 + k) * T_LEN + 2 * j + 1];
        Qs[tid - 64] = s;
    }
    __syncthreads();

    float r[4][4];
    float* rn = ramio + (size_t)n * NI * NJ;
    const float sc = 1.4426950408889634f / 128.f;            // log2(e)/C
    #pragma unroll
    for (int ii = 0; ii < 4; ++ii) {
        const int i = i0 + 4 * ty + ii;
        #pragma unroll
        for (int jj = 0; jj < 4; ++jj) {
            const int j = j0 + 4 * tx + jj;
            float val = 0.f;
            if (i < NI) {
                const float S = Ps[4 * ty + ii] + Qs[4 * tx + jj]
                              - 2.f * acc[ii][jj] + rn[i * NJ + j];
                val = exp2f(S * sc);
                if (val < 0.5f) val = 0.f;                   // dead (RAM>=1), kept for fidelity
                rn[i * NJ + j] = val;
            }
            r[ii][jj] = val;
        }
    }
    __syncthreads();
    // partial column sums over this block's 64 rows (invalid rows contribute 0)
    #pragma unroll
    for (int jj = 0; jj < 4; ++jj)
        s1[ty][4 * tx + jj] = r[0][jj] + r[1][jj] + r[2][jj] + r[3][jj];
    __syncthreads();
    if (tid < 64) {
        float s = 0.f;
        #pragma unroll
        for (int k = 0; k < 16; ++k) s += s1[k][tid];
        pda[(n * 5 + ib) * NJ + j0 + tid] = s;
    }
}

// ---- K4: per-row normalized sum: rowsum_i = rsqrt(db_i) * sum_j RAM*rsqrt(da_j)
__global__ __launch_bounds__(256) void k_row(const float* __restrict__ ram,
                                             const float* __restrict__ pda,
                                             float* __restrict__ rowsum) {
    const int ic = blockIdx.x, n = blockIdx.y;
    __shared__ float w_s[NJ];
    const int tid = threadIdx.x;
    {
        float da = 0.f;
        #pragma unroll
        for (int k = 0; k < 5; ++k) da += pda[(n * 5 + k) * NJ + tid];
        w_s[tid] = rsqrtf(da);                               // da >= 257, eps negligible
    }
    __syncthreads();
    const int wv = tid >> 6, lane = tid & 63;
    #pragma unroll
    for (int rr = 0; rr < 4; ++rr) {
        const int i = ic * 16 + wv * 4 + rr;
        if (i >= NI) continue;
        const float* rrow = ram + ((size_t)n * NI + i) * NJ;
        float t0 = 0.f, db = 0.f;
        #pragma unroll
        for (int k = 0; k < 4; ++k) {
            const float v = rrow[lane + 64 * k];
            db += v;
            t0 += v * w_s[lane + 64 * k];
        }
        #pragma unroll
        for (int off = 32; off; off >>= 1) {
            db += __shfl_xor(db, off, 64);
            t0 += __shfl_xor(t0, off, 64);
        }
        if (lane == 0) rowsum[n * NI + i] = t0 * rsqrtf(db);
    }
}

// ---- K5: out[n,c,t] = x[n,c,t] * 2*rowsum[n, t>>1]
__global__ __launch_bounds__(256) void k_apply(const float* __restrict__ x,
                                               const float* __restrict__ rowsum,
                                               float* __restrict__ out) {
    const int idx = blockIdx.x * 256 + threadIdx.x;
    const int t = idx % T_LEN;
    const int n = idx / (C_CH * T_LEN);
    out[idx] = x[idx] * (2.0f * rowsum[n * NI + (t >> 1)]);
}

extern "C" void kernel_launch(void* const* d_in, const int* in_sizes, int n_in,
                              void* d_out, int out_size, void* d_ws, size_t ws_size,
                              hipStream_t stream) {
    const float* x = (const float*)d_in[0];
    float* out = (float*)d_out;
    float* ws = (float*)d_ws;
    float* d2p  = ws + D2P_OFF;
    float* corr = ws + CORR_OFF;   // becomes RAM in-place
    float* pda  = ws + PDA_OFF;
    float* rs   = ws + RS_OFF;

    k_prep<<<dim3(N_B, 16), 512, 0, stream>>>(x, d2p, corr);
    k_corr<<<512, 256, 0, stream>>>(x, corr);
    k_gemm<<<dim3(4, 5, N_B), 256, 0, stream>>>(x, d2p, corr, pda);
    k_row<<<dim3(17, N_B), 256, 0, stream>>>(corr, pda, rs);
    const int total = N_B * C_CH * T_LEN;                    // 1,050,624 = 4104*256
    k_apply<<<total / 256, 256, 0, stream>>>(x, rs, out);
}